// Round 7
// baseline (353.627 us; speedup 1.0000x reference)
//
#include <hip/hip_runtime.h>

#define HH 64

static __global__ void k_set_ones(unsigned char* __restrict__ p, int n){
  int i = blockIdx.x * blockDim.x + threadIdx.x;
  if (i < n) p[i] = 1;
}

// one-time: w2t[j*64+i] = w2[i*64+j] so layer-2 scalar loads are contiguous in k
static __global__ void k_prep_w2t(const float* __restrict__ w2, float* __restrict__ w2t){
  int t = blockIdx.x * 256 + threadIdx.x;   // 16 blocks x 256 = 4096
  w2t[t] = w2[(t & 63) * HH + (t >> 6)];
}

// MLP core: 1 point per lane, h1[64] in VGPRs. ALL weight/bias indices are
// wave-uniform -> compiler emits scalar (s_load) reads into SGPRs; v_fma takes
// the SGPR operand directly. No LDS, no per-lane weight loads.
// launch_bounds(256,4): 128-VGPR cap, need ~72 -> no spill, 4 waves/EU.
__device__ __forceinline__ float mlp_eval(
    const float* __restrict__ w1, const float* __restrict__ b1,
    const float* __restrict__ w2t, const float* __restrict__ b2,
    const float* __restrict__ w3, const float* __restrict__ b3,
    float x, float y, float z)
{
  float h1[HH];
  #pragma unroll
  for (int i = 0; i < HH; ++i){
    float v = b1[i];
    v = fmaf(x, w1[i],        v);
    v = fmaf(y, w1[HH + i],   v);
    v = fmaf(z, w1[2*HH + i], v);
    h1[i] = fmaxf(v, 0.0f);
  }
  float o = b3[0];
  #pragma unroll 2
  for (int j = 0; j < HH; ++j){
    float acc = b2[j];
    const float* wr = &w2t[j*HH];
    #pragma unroll
    for (int k = 0; k < HH; ++k) acc = fmaf(h1[k], wr[k], acc);
    o = fmaf(fmaxf(acc, 0.0f), w3[j], o);
  }
  return 1.0f / (1.0f + expf(-o));
}

// ---------------- dense MLP eval (R=17, 33) ----------------
static __global__ __launch_bounds__(256, 4) void k_eval_mlp(
    const float* __restrict__ w1, const float* __restrict__ b1,
    const float* __restrict__ w2t, const float* __restrict__ b2,
    const float* __restrict__ w3, const float* __restrict__ b3,
    float* __restrict__ out, int R, int s)
{
  const unsigned int n = (unsigned int)R * (unsigned int)R * (unsigned int)R;
  unsigned int pid = blockIdx.x * 256u + threadIdx.x;
  if (pid >= n) return;
  const unsigned int c = pid % (unsigned int)R;
  const unsigned int r = pid / (unsigned int)R;
  const unsigned int b = r % (unsigned int)R;
  const unsigned int a = r / (unsigned int)R;
  const float inv129x2 = 2.0f / 129.0f;
  const float x = ((float)(c * (unsigned int)s) + 0.5f) * inv129x2 - 1.0f;
  const float y = ((float)(b * (unsigned int)s) + 0.5f) * inv129x2 - 1.0f;
  const float z = ((float)(a * (unsigned int)s) + 0.5f) * inv129x2 - 1.0f;
  out[pid] = mlp_eval(w1, b1, w2t, b2, w3, b3, x, y, z);
}

// ------------- sparse MLP eval over compacted index list (R=65, 129) -----------
static __global__ __launch_bounds__(256, 4) void k_eval_sparse(
    const float* __restrict__ w1, const float* __restrict__ b1,
    const float* __restrict__ w2t, const float* __restrict__ b2,
    const float* __restrict__ w3, const float* __restrict__ b3,
    const int* __restrict__ idxl, const unsigned int* __restrict__ cnt,
    const float* __restrict__ occ_i,
    float* __restrict__ out, unsigned char* __restrict__ mism,
    int R, int s, unsigned int n)
{
  unsigned int count = *cnt;
  if (count > n) count = n;               // guard vs stale ws during profiling replay
  const unsigned int slot = blockIdx.x * 256u + threadIdx.x;
  if (slot >= count) return;
  const unsigned int pid = (unsigned int)idxl[slot];

  const unsigned int c = pid % (unsigned int)R;
  const unsigned int r = pid / (unsigned int)R;
  const unsigned int b = r % (unsigned int)R;
  const unsigned int a = r / (unsigned int)R;
  const float inv129x2 = 2.0f / 129.0f;
  const float x = ((float)(c * (unsigned int)s) + 0.5f) * inv129x2 - 1.0f;
  const float y = ((float)(b * (unsigned int)s) + 0.5f) * inv129x2 - 1.0f;
  const float z = ((float)(a * (unsigned int)s) + 0.5f) * inv129x2 - 1.0f;

  float ot = mlp_eval(w1, b1, w2t, b2, w3, b3, x, y, z);
  out[pid] = ot;
  mism[pid] = ((occ_i[pid] - 0.5f) * (ot - 0.5f) < 0.0f) ? (unsigned char)1 : (unsigned char)0;
}

// ---- upsample + seed + calc + zero conf/upd + init occ_out=occ_i (fused) ----
static __global__ __launch_bounds__(256) void k_resize_b0(
    const float* __restrict__ prev,              // Rp^3
    const unsigned char* __restrict__ calc_prev, // Rp^3
    float* __restrict__ occ_i,                   // R^3
    float* __restrict__ occ_out,                 // R^3 (pre-combine init)
    unsigned char* __restrict__ bnd0,            // R^3 seed
    unsigned char* __restrict__ calc_out,        // R^3
    unsigned char* __restrict__ confA,
    unsigned char* __restrict__ confB,
    unsigned char* __restrict__ upd,
    int R, int Rp)
{
  const unsigned int n = (unsigned int)R * (unsigned int)R * (unsigned int)R;
  unsigned int gid = blockIdx.x * 256u + threadIdx.x;
  if (gid >= n) return;
  int c = (int)(gid % (unsigned int)R);
  unsigned int r = gid / (unsigned int)R;
  int b = (int)(r % (unsigned int)R);
  int a = (int)(r / (unsigned int)R);
  int a0 = a >> 1, da = a & 1;
  int b0i = b >> 1, db = b & 1;
  int c0 = c >> 1, dc = c & 1;
  float sum = 0.0f;
  int cnt = 0;
  const int tot = (da + 1) * (db + 1) * (dc + 1);
  for (int dz = 0; dz <= da; ++dz)
    for (int dy = 0; dy <= db; ++dy)
      for (int dx = 0; dx <= dc; ++dx){
        float v = prev[((unsigned int)(a0 + dz) * (unsigned int)Rp + (unsigned int)(b0i + dy)) * (unsigned int)Rp + (unsigned int)(c0 + dx)];
        sum += v;
        cnt += (v > 0.5f) ? 1 : 0;
      }
  float oi = sum / (float)tot;
  occ_i[gid] = oi;
  occ_out[gid] = oi;
  bnd0[gid] = (cnt > 0 && cnt < tot) ? 1 : 0;
  calc_out[gid] = ((da | db | dc) == 0)
      ? calc_prev[((unsigned int)a0 * (unsigned int)Rp + (unsigned int)b0i) * (unsigned int)Rp + (unsigned int)c0]
      : (unsigned char)0;
  confA[gid] = 0; confB[gid] = 0; upd[gid] = 0;
}

// ---- dense variant with mism + occ_out init (R=33 path) ----
static __global__ __launch_bounds__(256) void k_resize_boundary(
    const float* __restrict__ prev, const float* __restrict__ occ_true,
    const unsigned char* __restrict__ calc_prev,
    float* __restrict__ occ_i, float* __restrict__ occ_out,
    unsigned char* __restrict__ bnd0,
    unsigned char* __restrict__ mism, unsigned char* __restrict__ calc_out,
    int R, int Rp)
{
  const unsigned int n = (unsigned int)R * (unsigned int)R * (unsigned int)R;
  unsigned int gid = blockIdx.x * 256u + threadIdx.x;
  if (gid >= n) return;
  int c = (int)(gid % (unsigned int)R);
  unsigned int r = gid / (unsigned int)R;
  int b = (int)(r % (unsigned int)R);
  int a = (int)(r / (unsigned int)R);
  int a0 = a >> 1, da = a & 1;
  int b0i = b >> 1, db = b & 1;
  int c0 = c >> 1, dc = c & 1;
  float sum = 0.0f;
  int cnt = 0;
  const int tot = (da + 1) * (db + 1) * (dc + 1);
  for (int dz = 0; dz <= da; ++dz)
    for (int dy = 0; dy <= db; ++dy)
      for (int dx = 0; dx <= dc; ++dx){
        float v = prev[((unsigned int)(a0 + dz) * (unsigned int)Rp + (unsigned int)(b0i + dy)) * (unsigned int)Rp + (unsigned int)(c0 + dx)];
        sum += v;
        cnt += (v > 0.5f) ? 1 : 0;
      }
  float oi = sum / (float)tot;
  occ_i[gid] = oi;
  occ_out[gid] = oi;
  bnd0[gid] = (cnt > 0 && cnt < tot) ? 1 : 0;
  mism[gid] = ((oi - 0.5f) * (occ_true[gid] - 0.5f) < 0.0f) ? 1 : 0;
  calc_out[gid] = ((da | db | dc) == 0)
      ? calc_prev[((unsigned int)a0 * (unsigned int)Rp + (unsigned int)b0i) * (unsigned int)Rp + (unsigned int)c0]
      : (unsigned char)0;
}

// ---- separable 7-wide (radius-3) dilation: x, y, z passes ----
static __global__ __launch_bounds__(256) void k_dil7x(
    const unsigned char* __restrict__ in, unsigned char* __restrict__ outp, int R)
{
  const unsigned int n = (unsigned int)R * (unsigned int)R * (unsigned int)R;
  unsigned int gid = blockIdx.x * 256u + threadIdx.x;
  if (gid >= n) return;
  int c = (int)(gid % (unsigned int)R);
  int g = (int)gid;
  int m = 0;
  #pragma unroll
  for (int d = -3; d <= 3; ++d){
    int q = c + d;
    if (q >= 0 && q < R) m |= in[g + d];
  }
  outp[gid] = (unsigned char)(m ? 1 : 0);
}

static __global__ __launch_bounds__(256) void k_dil7y(
    const unsigned char* __restrict__ in, unsigned char* __restrict__ outp, int R)
{
  const unsigned int n = (unsigned int)R * (unsigned int)R * (unsigned int)R;
  unsigned int gid = blockIdx.x * 256u + threadIdx.x;
  if (gid >= n) return;
  unsigned int r = gid / (unsigned int)R;
  int b = (int)(r % (unsigned int)R);
  int g = (int)gid;
  int m = 0;
  #pragma unroll
  for (int d = -3; d <= 3; ++d){
    int q = b + d;
    if (q >= 0 && q < R) m |= in[g + d * R];
  }
  outp[gid] = (unsigned char)(m ? 1 : 0);
}

// z-pass + per-block candidate count (fused)
static __global__ __launch_bounds__(256) void k_dil7z_count(
    const unsigned char* __restrict__ in, unsigned char* __restrict__ outp,
    unsigned int* __restrict__ bcnt, int R)
{
  const unsigned int n = (unsigned int)R * (unsigned int)R * (unsigned int)R;
  unsigned int gid = blockIdx.x * 256u + threadIdx.x;
  int m = 0;
  if (gid < n){
    int a = (int)(gid / ((unsigned int)R * (unsigned int)R));
    int g = (int)gid;
    int RR = R * R;
    #pragma unroll
    for (int d = -3; d <= 3; ++d){
      int q = a + d;
      if (q >= 0 && q < R) m |= in[g + d * RR];
    }
    outp[gid] = (unsigned char)(m ? 1 : 0);
  }
  unsigned long long bm = __ballot(m != 0);
  __shared__ unsigned int wc[4];
  int wid = (int)(threadIdx.x >> 6);
  if ((threadIdx.x & 63u) == 0) wc[wid] = (unsigned int)__popcll(bm);
  __syncthreads();
  if (threadIdx.x == 0) bcnt[blockIdx.x] = wc[0] + wc[1] + wc[2] + wc[3];
}

// single block, 1024 threads: exclusive scan of nb block counts (nb <= 8387)
static __global__ __launch_bounds__(1024) void k_scan(
    unsigned int* __restrict__ bcnt, unsigned int nb, unsigned int* __restrict__ total)
{
  __shared__ unsigned int part[1024];
  const unsigned int t = threadIdx.x;
  const unsigned int chunk = (nb + 1023u) / 1024u;
  const unsigned int beg = t * chunk;
  const unsigned int end = (beg + chunk < nb) ? (beg + chunk) : nb;
  unsigned int s = 0;
  for (unsigned int i = beg; i < end; ++i) s += bcnt[i];
  part[t] = s;
  __syncthreads();
  for (int offd = 1; offd < 1024; offd <<= 1){
    unsigned int v = (t >= (unsigned int)offd) ? part[t - offd] : 0u;
    __syncthreads();
    part[t] += v;
    __syncthreads();
  }
  unsigned int run = (t == 0) ? 0u : part[t - 1];
  for (unsigned int i = beg; i < end; ++i){
    unsigned int v = bcnt[i];
    bcnt[i] = run;
    run += v;
  }
  if (t == 1023) *total = part[1023];
}

static __global__ __launch_bounds__(256) void k_scatter(
    const unsigned char* __restrict__ cand, const unsigned int* __restrict__ boff,
    int* __restrict__ idxl, unsigned int n)
{
  unsigned int gid = blockIdx.x * 256u + threadIdx.x;
  bool pred = (gid < n) && (cand[gid] != 0);
  unsigned long long m = __ballot(pred);
  __shared__ unsigned int wbase[4];
  int wid = (int)(threadIdx.x >> 6);
  int lane = (int)(threadIdx.x & 63u);
  if (lane == 0) wbase[wid] = (unsigned int)__popcll(m);
  __syncthreads();
  if (threadIdx.x == 0){
    unsigned int b = boff[blockIdx.x];
    unsigned int t0 = wbase[0], t1 = wbase[1], t2 = wbase[2];
    wbase[0] = b; wbase[1] = b + t0; wbase[2] = b + t0 + t1; wbase[3] = b + t0 + t1 + t2;
  }
  __syncthreads();
  if (pred){
    int pre = __popcll(m & ((1ull << lane) - 1ull));
    idxl[wbase[wid] + (unsigned int)pre] = (int)gid;
  }
}

// ---- sparse dilate-step; final step also commits occ_true where upd ----
static __global__ __launch_bounds__(256) void k_dilate_sparse(
    const int* __restrict__ idxl, const unsigned int* __restrict__ cnt,
    const unsigned char* __restrict__ src, const unsigned char* __restrict__ mism,
    unsigned char* __restrict__ calc, unsigned char* __restrict__ conf_out,
    unsigned char* __restrict__ upd, int R, int final_step,
    const float* __restrict__ occ_true, float* __restrict__ occ_out,
    unsigned int n)
{
  unsigned int count = *cnt;
  if (count > n) count = n;               // guard vs stale ws during profiling replay
  for (unsigned int slot = blockIdx.x * 256u + threadIdx.x; slot < count;
       slot += gridDim.x * 256u){
    int gid = idxl[slot];
    int c = gid % R;
    int r = gid / R;
    int b = r % R;
    int a = r / R;
    int m = 0;
    for (int dz = -1; dz <= 1; ++dz){
      int az = a + dz; if (az < 0 || az >= R) continue;
      for (int dy = -1; dy <= 1; ++dy){
        int by = b + dy; if (by < 0 || by >= R) continue;
        for (int dx = -1; dx <= 1; ++dx){
          int cx = c + dx; if (cx < 0 || cx >= R) continue;
          m |= src[(az * R + by) * R + cx];
        }
      }
    }
    unsigned char nb = (m && !calc[gid]) ? (unsigned char)1 : (unsigned char)0;
    conf_out[gid] = (nb && mism[gid]) ? (unsigned char)1 : (unsigned char)0;
    unsigned char u = upd[gid];
    if (nb){ calc[gid] = 1; if (!u){ upd[gid] = 1; u = 1; } }
    if (final_step && u) occ_out[gid] = occ_true[gid];
  }
}

// ---- dense dilate-step (R=33 path); final step commits occ_true ----
static __global__ __launch_bounds__(256) void k_dilate_step(
    const unsigned char* __restrict__ src, const unsigned char* __restrict__ mism,
    unsigned char* __restrict__ calc, unsigned char* __restrict__ conf_out,
    unsigned char* __restrict__ upd, int R, int first, int final_step,
    const float* __restrict__ occ_true, float* __restrict__ occ_out)
{
  const unsigned int n = (unsigned int)R * (unsigned int)R * (unsigned int)R;
  unsigned int gid = blockIdx.x * 256u + threadIdx.x;
  if (gid >= n) return;
  int c = (int)(gid % (unsigned int)R);
  unsigned int r = gid / (unsigned int)R;
  int b = (int)(r % (unsigned int)R);
  int a = (int)(r / (unsigned int)R);
  int m = 0;
  for (int dz = -1; dz <= 1; ++dz){
    int az = a + dz; if (az < 0 || az >= R) continue;
    for (int dy = -1; dy <= 1; ++dy){
      int by = b + dy; if (by < 0 || by >= R) continue;
      for (int dx = -1; dx <= 1; ++dx){
        int cx = c + dx; if (cx < 0 || cx >= R) continue;
        m |= src[((unsigned int)az * (unsigned int)R + (unsigned int)by) * (unsigned int)R + (unsigned int)cx];
      }
    }
  }
  unsigned char nb = (m && !calc[gid]) ? (unsigned char)1 : (unsigned char)0;
  if (nb) calc[gid] = 1;
  conf_out[gid] = (nb && mism[gid]) ? (unsigned char)1 : (unsigned char)0;
  unsigned char u;
  if (first){ u = nb; upd[gid] = nb; }
  else { u = upd[gid]; if (nb && !u){ upd[gid] = 1; u = 1; } }
  if (final_step && u) occ_out[gid] = occ_true[gid];
}

extern "C" void kernel_launch(void* const* d_in, const int* in_sizes, int n_in,
                              void* d_out, int out_size, void* d_ws, size_t ws_size,
                              hipStream_t stream)
{
  const float* w1 = (const float*)d_in[0];
  const float* b1 = (const float*)d_in[1];
  const float* w2 = (const float*)d_in[2];
  const float* b2 = (const float*)d_in[3];
  const float* w3 = (const float*)d_in[4];
  const float* b3 = (const float*)d_in[5];
  float* out = (float*)d_out;

  const int NF = 129 * 129 * 129;  // 2146689
  const int NP = 65 * 65 * 65;
  char* ws = (char*)d_ws;
  size_t off = 0;
  auto alloc = [&](size_t bytes) -> void* {
    void* p = (void*)(ws + off);
    off += (bytes + 255) & ~(size_t)255;
    return p;
  };
  float* f_true  = (float*)alloc((size_t)NF * 4);
  float* f_occi  = (float*)alloc((size_t)NF * 4);
  float* f_prevA = (float*)alloc((size_t)NP * 4);
  float* f_prevB = (float*)alloc((size_t)NP * 4);
  float* f_w2t   = (float*)alloc((size_t)HH * HH * 4);
  int*   i_idx   = (int*)alloc((size_t)NF * 4);
  unsigned int* u_cnt  = (unsigned int*)alloc(256);
  unsigned int* u_bcnt = (unsigned int*)alloc(8448 * 4);
  unsigned char* b_b0    = (unsigned char*)alloc(NF);
  unsigned char* b_mism  = (unsigned char*)alloc(NF);
  unsigned char* b_confA = (unsigned char*)alloc(NF);
  unsigned char* b_confB = (unsigned char*)alloc(NF);
  unsigned char* b_calcA = (unsigned char*)alloc(NF);
  unsigned char* b_calcB = (unsigned char*)alloc(NF);
  unsigned char* b_upd   = (unsigned char*)alloc(NF);
  unsigned char* b_cand  = (unsigned char*)alloc(NF);
  unsigned char* b_tmp   = (unsigned char*)alloc(NF);
  (void)ws_size;

  k_prep_w2t<<<16, 256, 0, stream>>>(w2, f_w2t);

  // Level 0: R=17 dense eval; calculated mask all-true.
  {
    int R = 17, s = 8;
    int n = R * R * R;
    int blocks = (n + 255) / 256;
    k_eval_mlp<<<blocks, 256, 0, stream>>>(w1, b1, f_w2t, b2, w3, b3, f_prevA, R, s);
    k_set_ones<<<blocks, 256, 0, stream>>>(b_calcA, n);
  }

  int Rp = 17;
  float* prev = f_prevA;
  unsigned char* calcP = b_calcA;
  unsigned char* calcC = b_calcB;
  for (int li = 1; li <= 3; ++li){
    int R = 2 * Rp - 1;
    int s = 128 / (R - 1);
    unsigned int n = (unsigned int)R * (unsigned int)R * (unsigned int)R;
    int blocks = (int)((n + 255u) / 256u);
    float* occ_out = (li == 3) ? out : ((prev == f_prevA) ? f_prevB : f_prevA);

    if (R == 33){
      // dense path (small)
      k_eval_mlp<<<blocks, 256, 0, stream>>>(w1, b1, f_w2t, b2, w3, b3, f_true, R, s);
      k_resize_boundary<<<blocks, 256, 0, stream>>>(prev, f_true, calcP, f_occi, occ_out, b_b0, b_mism, calcC, R, Rp);
      k_dilate_step<<<blocks, 256, 0, stream>>>(b_b0,    b_mism, calcC, b_confA, b_upd, R, 1, 0, f_true, occ_out);
      k_dilate_step<<<blocks, 256, 0, stream>>>(b_confA, b_mism, calcC, b_confB, b_upd, R, 0, 0, f_true, occ_out);
      k_dilate_step<<<blocks, 256, 0, stream>>>(b_confB, b_mism, calcC, b_confA, b_upd, R, 0, 1, f_true, occ_out);
    } else {
      // sparse path: eval only on C = dilate^3(seed) (separable 7-box = d^3)
      k_resize_b0<<<blocks, 256, 0, stream>>>(prev, calcP, f_occi, occ_out, b_b0, calcC,
                                              b_confA, b_confB, b_upd, R, Rp);
      k_dil7x<<<blocks, 256, 0, stream>>>(b_b0,  b_tmp,  R);
      k_dil7y<<<blocks, 256, 0, stream>>>(b_tmp, b_cand, R);
      k_dil7z_count<<<blocks, 256, 0, stream>>>(b_cand, b_tmp, u_bcnt, R);
      k_scan<<<1, 1024, 0, stream>>>(u_bcnt, (unsigned int)blocks, u_cnt);
      k_scatter<<<blocks, 256, 0, stream>>>(b_tmp, u_bcnt, i_idx, n);
      k_eval_sparse<<<blocks, 256, 0, stream>>>(
          w1, b1, f_w2t, b2, w3, b3, i_idx, u_cnt, f_occi, f_true, b_mism, R, s, n);
      int sblocks = blocks < 4096 ? blocks : 4096;
      k_dilate_sparse<<<sblocks, 256, 0, stream>>>(i_idx, u_cnt, b_b0,    b_mism, calcC, b_confA, b_upd, R, 0, f_true, occ_out, n);
      k_dilate_sparse<<<sblocks, 256, 0, stream>>>(i_idx, u_cnt, b_confA, b_mism, calcC, b_confB, b_upd, R, 0, f_true, occ_out, n);
      k_dilate_sparse<<<sblocks, 256, 0, stream>>>(i_idx, u_cnt, b_confB, b_mism, calcC, b_confA, b_upd, R, 1, f_true, occ_out, n);
    }

    prev = occ_out;
    unsigned char* tmpc = calcP; calcP = calcC; calcC = tmpc;
    Rp = R;
  }
  (void)in_sizes; (void)n_in; (void)out_size;
}

// Round 8
// 307.956 us; speedup vs baseline: 1.1483x; 1.1483x over previous
//
#include <hip/hip_runtime.h>

#define HH 64

static __global__ void k_set_ones(unsigned char* __restrict__ p, int n){
  int i = blockIdx.x * blockDim.x + threadIdx.x;
  if (i < n) p[i] = 1;
}

// one-time: w2t[j*64+i] = w2[i*64+j]
static __global__ void k_prep_w2t(const float* __restrict__ w2, float* __restrict__ w2t){
  int t = blockIdx.x * 256 + threadIdx.x;   // 16 blocks x 256 = 4096
  w2t[t] = w2[(t & 63) * HH + (t >> 6)];
}

// ===================== pair-MLP core =====================
// 2 points per lane, hidden dim half-split across lane pair (l, l^32).
// Per j: 8 ds_read_b128 (2-addr broadcast, free per m136) + 2 shfl feed
// 64 lane-FMAs -> ~11 LDS instrs/point (vs 18 in the 1-pt scheme; LDS pipe
// at ~5.8 cyc/instr is the bottleneck). b2/w3/b3 read from global
// (wave-uniform -> scalar pipe, off the LDS pipe).
// amdgpu_waves_per_eu(4,4): pin allocator at 128-VGPR budget (need ~115);
// min-only bounds let the heuristic target 8 waves and spill (round 2).
__device__ __forceinline__ void mlp_pair(
    const float* __restrict__ sw1,   // LDS: x[64] y[64] z[64] b1[64]
    const float* __restrict__ sw2t,  // LDS: 4096
    const float* __restrict__ b2, const float* __restrict__ w3,
    const float* __restrict__ b3,
    float xA, float yA, float zA, float xB, float yB, float zB,
    float& outA, float& outB)
{
  const int ibase = ((threadIdx.x & 63) >> 5) * 32;
  float h1a[32], h1b[32];
  #pragma unroll
  for (int k = 0; k < 32; k += 4){
    const float4 wx = *(const float4*)&sw1[      ibase + k];
    const float4 wy = *(const float4*)&sw1[ 64 + ibase + k];
    const float4 wz = *(const float4*)&sw1[128 + ibase + k];
    const float4 bb = *(const float4*)&sw1[192 + ibase + k];
    h1a[k+0] = fmaxf(fmaf(xA,wx.x,fmaf(yA,wy.x,fmaf(zA,wz.x,bb.x))),0.f);
    h1a[k+1] = fmaxf(fmaf(xA,wx.y,fmaf(yA,wy.y,fmaf(zA,wz.y,bb.y))),0.f);
    h1a[k+2] = fmaxf(fmaf(xA,wx.z,fmaf(yA,wy.z,fmaf(zA,wz.z,bb.z))),0.f);
    h1a[k+3] = fmaxf(fmaf(xA,wx.w,fmaf(yA,wy.w,fmaf(zA,wz.w,bb.w))),0.f);
    h1b[k+0] = fmaxf(fmaf(xB,wx.x,fmaf(yB,wy.x,fmaf(zB,wz.x,bb.x))),0.f);
    h1b[k+1] = fmaxf(fmaf(xB,wx.y,fmaf(yB,wy.y,fmaf(zB,wz.y,bb.y))),0.f);
    h1b[k+2] = fmaxf(fmaf(xB,wx.z,fmaf(yB,wy.z,fmaf(zB,wz.z,bb.z))),0.f);
    h1b[k+3] = fmaxf(fmaf(xB,wx.w,fmaf(yB,wy.w,fmaf(zB,wz.w,bb.w))),0.f);
  }
  float oa = b3[0], ob = oa;
  #pragma unroll 1
  for (int j = 0; j < HH; ++j){
    const float4* wrow = (const float4*)&sw2t[j*HH + ibase];
    float a0 = 0.f, a1 = 0.f, c0 = 0.f, c1 = 0.f;   // 4 indep FMA chains
    #pragma unroll
    for (int q = 0; q < 8; q += 2){
      const float4 w0 = wrow[q];
      const float4 w1q = wrow[q+1];
      a0 = fmaf(h1a[4*q+0], w0.x, a0);
      a0 = fmaf(h1a[4*q+1], w0.y, a0);
      a0 = fmaf(h1a[4*q+2], w0.z, a0);
      a0 = fmaf(h1a[4*q+3], w0.w, a0);
      a1 = fmaf(h1a[4*q+4], w1q.x, a1);
      a1 = fmaf(h1a[4*q+5], w1q.y, a1);
      a1 = fmaf(h1a[4*q+6], w1q.z, a1);
      a1 = fmaf(h1a[4*q+7], w1q.w, a1);
      c0 = fmaf(h1b[4*q+0], w0.x, c0);
      c0 = fmaf(h1b[4*q+1], w0.y, c0);
      c0 = fmaf(h1b[4*q+2], w0.z, c0);
      c0 = fmaf(h1b[4*q+3], w0.w, c0);
      c1 = fmaf(h1b[4*q+4], w1q.x, c1);
      c1 = fmaf(h1b[4*q+5], w1q.y, c1);
      c1 = fmaf(h1b[4*q+6], w1q.z, c1);
      c1 = fmaf(h1b[4*q+7], w1q.w, c1);
    }
    float accA = a0 + a1, accB = c0 + c1;
    accA += __shfl_xor(accA, 32);
    accB += __shfl_xor(accB, 32);
    const float bj = b2[j], wj = w3[j];
    oa = fmaf(fmaxf(accA + bj, 0.f), wj, oa);
    ob = fmaf(fmaxf(accB + bj, 0.f), wj, ob);
  }
  outA = 1.f / (1.f + expf(-oa));
  outB = 1.f / (1.f + expf(-ob));
}

#define STAGE_WEIGHTS()                                            \
  __shared__ float sw1[4*HH];                                      \
  __shared__ float sw2t[HH*HH];                                    \
  {                                                                \
    const int t0 = threadIdx.x;                                    \
    if (t0 < 3*HH) sw1[t0] = w1[t0];                               \
    else sw1[t0] = b1[t0 - 3*HH];                                  \
    const float4* s4 = (const float4*)w2t;                         \
    float4* d4 = (float4*)sw2t;                                    \
    for (int i4 = t0; i4 < HH*HH/4; i4 += 256) d4[i4] = s4[i4];    \
    __syncthreads();                                               \
  }

// ---------------- dense pair eval (R=17, 33): block = 256 points ----------------
static __global__ __launch_bounds__(256)
__attribute__((amdgpu_waves_per_eu(4,4)))
void k_eval_mlp(
    const float* __restrict__ w1, const float* __restrict__ b1,
    const float* __restrict__ w2t, const float* __restrict__ b2,
    const float* __restrict__ w3, const float* __restrict__ b3,
    float* __restrict__ out, int R, int s)
{
  STAGE_WEIGHTS();
  const unsigned int n = (unsigned int)R * (unsigned int)R * (unsigned int)R;
  const int lane = threadIdx.x & 63;
  const int wid = threadIdx.x >> 6;
  const unsigned int base = blockIdx.x * 256u + (unsigned int)(wid * 64 + (lane & 31));
  const unsigned int pidA = base < n ? base : (n - 1u);
  const unsigned int pB = base + 32u;
  const unsigned int pidB = pB < n ? pB : (n - 1u);
  const float inv129x2 = 2.0f / 129.0f;
  unsigned int cA = pidA % (unsigned int)R, rA = pidA / (unsigned int)R;
  unsigned int cB = pidB % (unsigned int)R, rB = pidB / (unsigned int)R;
  const float xA = ((float)(cA * (unsigned int)s) + 0.5f) * inv129x2 - 1.0f;
  const float yA = ((float)((rA % (unsigned int)R) * (unsigned int)s) + 0.5f) * inv129x2 - 1.0f;
  const float zA = ((float)((rA / (unsigned int)R) * (unsigned int)s) + 0.5f) * inv129x2 - 1.0f;
  const float xB = ((float)(cB * (unsigned int)s) + 0.5f) * inv129x2 - 1.0f;
  const float yB = ((float)((rB % (unsigned int)R) * (unsigned int)s) + 0.5f) * inv129x2 - 1.0f;
  const float zB = ((float)((rB / (unsigned int)R) * (unsigned int)s) + 0.5f) * inv129x2 - 1.0f;
  float oA, oB;
  mlp_pair(sw1, sw2t, b2, w3, b3, xA, yA, zA, xB, yB, zB, oA, oB);
  if ((threadIdx.x & 63) < 32){
    if (base < n) out[pidA] = oA;
    if (pB < n)   out[pidB] = oB;
  }
}

// ------------- sparse pair eval over compacted index list (R=65, 129) -----------
static __global__ __launch_bounds__(256)
__attribute__((amdgpu_waves_per_eu(4,4)))
void k_eval_sparse(
    const float* __restrict__ w1, const float* __restrict__ b1,
    const float* __restrict__ w2t, const float* __restrict__ b2,
    const float* __restrict__ w3, const float* __restrict__ b3,
    const int* __restrict__ idxl, const unsigned int* __restrict__ cnt,
    const float* __restrict__ occ_i,
    float* __restrict__ out, unsigned char* __restrict__ mism,
    int R, int s, unsigned int n)
{
  unsigned int count = *cnt;
  if (count > n) count = n;               // guard vs stale ws during profiling replay
  if (blockIdx.x * 256u >= count) return; // block-uniform early exit
  STAGE_WEIGHTS();
  const int lane = threadIdx.x & 63;
  const int wid = threadIdx.x >> 6;
  const unsigned int slotA = blockIdx.x * 256u + (unsigned int)(wid * 64 + (lane & 31));
  const unsigned int slotB = slotA + 32u;
  const bool vA = slotA < count, vB = slotB < count;
  const unsigned int pidA = (unsigned int)idxl[vA ? slotA : 0];
  const unsigned int pidB = (unsigned int)idxl[vB ? slotB : 0];
  const float inv129x2 = 2.0f / 129.0f;
  unsigned int cA = pidA % (unsigned int)R, rA = pidA / (unsigned int)R;
  unsigned int cB = pidB % (unsigned int)R, rB = pidB / (unsigned int)R;
  const float xA = ((float)(cA * (unsigned int)s) + 0.5f) * inv129x2 - 1.0f;
  const float yA = ((float)((rA % (unsigned int)R) * (unsigned int)s) + 0.5f) * inv129x2 - 1.0f;
  const float zA = ((float)((rA / (unsigned int)R) * (unsigned int)s) + 0.5f) * inv129x2 - 1.0f;
  const float xB = ((float)(cB * (unsigned int)s) + 0.5f) * inv129x2 - 1.0f;
  const float yB = ((float)((rB % (unsigned int)R) * (unsigned int)s) + 0.5f) * inv129x2 - 1.0f;
  const float zB = ((float)((rB / (unsigned int)R) * (unsigned int)s) + 0.5f) * inv129x2 - 1.0f;
  float oA, oB;
  mlp_pair(sw1, sw2t, b2, w3, b3, xA, yA, zA, xB, yB, zB, oA, oB);
  if ((threadIdx.x & 63) < 32){
    if (vA){
      out[pidA] = oA;
      mism[pidA] = ((occ_i[pidA] - 0.5f) * (oA - 0.5f) < 0.0f) ? (unsigned char)1 : (unsigned char)0;
    }
    if (vB){
      out[pidB] = oB;
      mism[pidB] = ((occ_i[pidB] - 0.5f) * (oB - 0.5f) < 0.0f) ? (unsigned char)1 : (unsigned char)0;
    }
  }
}

// ---- upsample + seed + calc + zero conf/upd + init occ_out=occ_i (fused) ----
static __global__ __launch_bounds__(256) void k_resize_b0(
    const float* __restrict__ prev,
    const unsigned char* __restrict__ calc_prev,
    float* __restrict__ occ_i, float* __restrict__ occ_out,
    unsigned char* __restrict__ bnd0, unsigned char* __restrict__ calc_out,
    unsigned char* __restrict__ confA, unsigned char* __restrict__ confB,
    unsigned char* __restrict__ upd, int R, int Rp)
{
  const unsigned int n = (unsigned int)R * (unsigned int)R * (unsigned int)R;
  unsigned int gid = blockIdx.x * 256u + threadIdx.x;
  if (gid >= n) return;
  int c = (int)(gid % (unsigned int)R);
  unsigned int r = gid / (unsigned int)R;
  int b = (int)(r % (unsigned int)R);
  int a = (int)(r / (unsigned int)R);
  int a0 = a >> 1, da = a & 1;
  int b0i = b >> 1, db = b & 1;
  int c0 = c >> 1, dc = c & 1;
  float sum = 0.0f;
  int cnt = 0;
  const int tot = (da + 1) * (db + 1) * (dc + 1);
  for (int dz = 0; dz <= da; ++dz)
    for (int dy = 0; dy <= db; ++dy)
      for (int dx = 0; dx <= dc; ++dx){
        float v = prev[((unsigned int)(a0 + dz) * (unsigned int)Rp + (unsigned int)(b0i + dy)) * (unsigned int)Rp + (unsigned int)(c0 + dx)];
        sum += v;
        cnt += (v > 0.5f) ? 1 : 0;
      }
  float oi = sum / (float)tot;
  occ_i[gid] = oi;
  occ_out[gid] = oi;
  bnd0[gid] = (cnt > 0 && cnt < tot) ? 1 : 0;
  calc_out[gid] = ((da | db | dc) == 0)
      ? calc_prev[((unsigned int)a0 * (unsigned int)Rp + (unsigned int)b0i) * (unsigned int)Rp + (unsigned int)c0]
      : (unsigned char)0;
  confA[gid] = 0; confB[gid] = 0; upd[gid] = 0;
}

// ---- dense variant with mism + occ_out init (R=33 path) ----
static __global__ __launch_bounds__(256) void k_resize_boundary(
    const float* __restrict__ prev, const float* __restrict__ occ_true,
    const unsigned char* __restrict__ calc_prev,
    float* __restrict__ occ_i, float* __restrict__ occ_out,
    unsigned char* __restrict__ bnd0,
    unsigned char* __restrict__ mism, unsigned char* __restrict__ calc_out,
    int R, int Rp)
{
  const unsigned int n = (unsigned int)R * (unsigned int)R * (unsigned int)R;
  unsigned int gid = blockIdx.x * 256u + threadIdx.x;
  if (gid >= n) return;
  int c = (int)(gid % (unsigned int)R);
  unsigned int r = gid / (unsigned int)R;
  int b = (int)(r % (unsigned int)R);
  int a = (int)(r / (unsigned int)R);
  int a0 = a >> 1, da = a & 1;
  int b0i = b >> 1, db = b & 1;
  int c0 = c >> 1, dc = c & 1;
  float sum = 0.0f;
  int cnt = 0;
  const int tot = (da + 1) * (db + 1) * (dc + 1);
  for (int dz = 0; dz <= da; ++dz)
    for (int dy = 0; dy <= db; ++dy)
      for (int dx = 0; dx <= dc; ++dx){
        float v = prev[((unsigned int)(a0 + dz) * (unsigned int)Rp + (unsigned int)(b0i + dy)) * (unsigned int)Rp + (unsigned int)(c0 + dx)];
        sum += v;
        cnt += (v > 0.5f) ? 1 : 0;
      }
  float oi = sum / (float)tot;
  occ_i[gid] = oi;
  occ_out[gid] = oi;
  bnd0[gid] = (cnt > 0 && cnt < tot) ? 1 : 0;
  mism[gid] = ((oi - 0.5f) * (occ_true[gid] - 0.5f) < 0.0f) ? 1 : 0;
  calc_out[gid] = ((da | db | dc) == 0)
      ? calc_prev[((unsigned int)a0 * (unsigned int)Rp + (unsigned int)b0i) * (unsigned int)Rp + (unsigned int)c0]
      : (unsigned char)0;
}

// ---- separable 7-wide (radius-3) dilation: x, y, z passes ----
static __global__ __launch_bounds__(256) void k_dil7x(
    const unsigned char* __restrict__ in, unsigned char* __restrict__ outp, int R)
{
  const unsigned int n = (unsigned int)R * (unsigned int)R * (unsigned int)R;
  unsigned int gid = blockIdx.x * 256u + threadIdx.x;
  if (gid >= n) return;
  int c = (int)(gid % (unsigned int)R);
  int g = (int)gid;
  int m = 0;
  #pragma unroll
  for (int d = -3; d <= 3; ++d){
    int q = c + d;
    if (q >= 0 && q < R) m |= in[g + d];
  }
  outp[gid] = (unsigned char)(m ? 1 : 0);
}

static __global__ __launch_bounds__(256) void k_dil7y(
    const unsigned char* __restrict__ in, unsigned char* __restrict__ outp, int R)
{
  const unsigned int n = (unsigned int)R * (unsigned int)R * (unsigned int)R;
  unsigned int gid = blockIdx.x * 256u + threadIdx.x;
  if (gid >= n) return;
  unsigned int r = gid / (unsigned int)R;
  int b = (int)(r % (unsigned int)R);
  int g = (int)gid;
  int m = 0;
  #pragma unroll
  for (int d = -3; d <= 3; ++d){
    int q = b + d;
    if (q >= 0 && q < R) m |= in[g + d * R];
  }
  outp[gid] = (unsigned char)(m ? 1 : 0);
}

static __global__ __launch_bounds__(256) void k_dil7z_count(
    const unsigned char* __restrict__ in, unsigned char* __restrict__ outp,
    unsigned int* __restrict__ bcnt, int R)
{
  const unsigned int n = (unsigned int)R * (unsigned int)R * (unsigned int)R;
  unsigned int gid = blockIdx.x * 256u + threadIdx.x;
  int m = 0;
  if (gid < n){
    int a = (int)(gid / ((unsigned int)R * (unsigned int)R));
    int g = (int)gid;
    int RR = R * R;
    #pragma unroll
    for (int d = -3; d <= 3; ++d){
      int q = a + d;
      if (q >= 0 && q < R) m |= in[g + d * RR];
    }
    outp[gid] = (unsigned char)(m ? 1 : 0);
  }
  unsigned long long bm = __ballot(m != 0);
  __shared__ unsigned int wc[4];
  int wid = (int)(threadIdx.x >> 6);
  if ((threadIdx.x & 63u) == 0) wc[wid] = (unsigned int)__popcll(bm);
  __syncthreads();
  if (threadIdx.x == 0) bcnt[blockIdx.x] = wc[0] + wc[1] + wc[2] + wc[3];
}

// single block, 1024 threads: exclusive scan of nb block counts (nb <= 8387)
static __global__ __launch_bounds__(1024) void k_scan(
    unsigned int* __restrict__ bcnt, unsigned int nb, unsigned int* __restrict__ total)
{
  __shared__ unsigned int part[1024];
  const unsigned int t = threadIdx.x;
  const unsigned int chunk = (nb + 1023u) / 1024u;
  const unsigned int beg = t * chunk;
  const unsigned int end = (beg + chunk < nb) ? (beg + chunk) : nb;
  unsigned int s = 0;
  for (unsigned int i = beg; i < end; ++i) s += bcnt[i];
  part[t] = s;
  __syncthreads();
  for (int offd = 1; offd < 1024; offd <<= 1){
    unsigned int v = (t >= (unsigned int)offd) ? part[t - offd] : 0u;
    __syncthreads();
    part[t] += v;
    __syncthreads();
  }
  unsigned int run = (t == 0) ? 0u : part[t - 1];
  for (unsigned int i = beg; i < end; ++i){
    unsigned int v = bcnt[i];
    bcnt[i] = run;
    run += v;
  }
  if (t == 1023) *total = part[1023];
}

static __global__ __launch_bounds__(256) void k_scatter(
    const unsigned char* __restrict__ cand, const unsigned int* __restrict__ boff,
    int* __restrict__ idxl, unsigned int n)
{
  unsigned int gid = blockIdx.x * 256u + threadIdx.x;
  bool pred = (gid < n) && (cand[gid] != 0);
  unsigned long long m = __ballot(pred);
  __shared__ unsigned int wbase[4];
  int wid = (int)(threadIdx.x >> 6);
  int lane = (int)(threadIdx.x & 63u);
  if (lane == 0) wbase[wid] = (unsigned int)__popcll(m);
  __syncthreads();
  if (threadIdx.x == 0){
    unsigned int b = boff[blockIdx.x];
    unsigned int t0 = wbase[0], t1 = wbase[1], t2 = wbase[2];
    wbase[0] = b; wbase[1] = b + t0; wbase[2] = b + t0 + t1; wbase[3] = b + t0 + t1 + t2;
  }
  __syncthreads();
  if (pred){
    int pre = __popcll(m & ((1ull << lane) - 1ull));
    idxl[wbase[wid] + (unsigned int)pre] = (int)gid;
  }
}

// ---- sparse dilate-step; final step also commits occ_true where upd ----
static __global__ __launch_bounds__(256) void k_dilate_sparse(
    const int* __restrict__ idxl, const unsigned int* __restrict__ cnt,
    const unsigned char* __restrict__ src, const unsigned char* __restrict__ mism,
    unsigned char* __restrict__ calc, unsigned char* __restrict__ conf_out,
    unsigned char* __restrict__ upd, int R, int final_step,
    const float* __restrict__ occ_true, float* __restrict__ occ_out,
    unsigned int n)
{
  unsigned int count = *cnt;
  if (count > n) count = n;
  for (unsigned int slot = blockIdx.x * 256u + threadIdx.x; slot < count;
       slot += gridDim.x * 256u){
    int gid = idxl[slot];
    int c = gid % R;
    int r = gid / R;
    int b = r % R;
    int a = r / R;
    int m = 0;
    for (int dz = -1; dz <= 1; ++dz){
      int az = a + dz; if (az < 0 || az >= R) continue;
      for (int dy = -1; dy <= 1; ++dy){
        int by = b + dy; if (by < 0 || by >= R) continue;
        for (int dx = -1; dx <= 1; ++dx){
          int cx = c + dx; if (cx < 0 || cx >= R) continue;
          m |= src[(az * R + by) * R + cx];
        }
      }
    }
    unsigned char nb = (m && !calc[gid]) ? (unsigned char)1 : (unsigned char)0;
    conf_out[gid] = (nb && mism[gid]) ? (unsigned char)1 : (unsigned char)0;
    unsigned char u = upd[gid];
    if (nb){ calc[gid] = 1; if (!u){ upd[gid] = 1; u = 1; } }
    if (final_step && u) occ_out[gid] = occ_true[gid];
  }
}

// ---- dense dilate-step (R=33 path); final step commits occ_true ----
static __global__ __launch_bounds__(256) void k_dilate_step(
    const unsigned char* __restrict__ src, const unsigned char* __restrict__ mism,
    unsigned char* __restrict__ calc, unsigned char* __restrict__ conf_out,
    unsigned char* __restrict__ upd, int R, int first, int final_step,
    const float* __restrict__ occ_true, float* __restrict__ occ_out)
{
  const unsigned int n = (unsigned int)R * (unsigned int)R * (unsigned int)R;
  unsigned int gid = blockIdx.x * 256u + threadIdx.x;
  if (gid >= n) return;
  int c = (int)(gid % (unsigned int)R);
  unsigned int r = gid / (unsigned int)R;
  int b = (int)(r % (unsigned int)R);
  int a = (int)(r / (unsigned int)R);
  int m = 0;
  for (int dz = -1; dz <= 1; ++dz){
    int az = a + dz; if (az < 0 || az >= R) continue;
    for (int dy = -1; dy <= 1; ++dy){
      int by = b + dy; if (by < 0 || by >= R) continue;
      for (int dx = -1; dx <= 1; ++dx){
        int cx = c + dx; if (cx < 0 || cx >= R) continue;
        m |= src[((unsigned int)az * (unsigned int)R + (unsigned int)by) * (unsigned int)R + (unsigned int)cx];
      }
    }
  }
  unsigned char nb = (m && !calc[gid]) ? (unsigned char)1 : (unsigned char)0;
  if (nb) calc[gid] = 1;
  conf_out[gid] = (nb && mism[gid]) ? (unsigned char)1 : (unsigned char)0;
  unsigned char u;
  if (first){ u = nb; upd[gid] = nb; }
  else { u = upd[gid]; if (nb && !u){ upd[gid] = 1; u = 1; } }
  if (final_step && u) occ_out[gid] = occ_true[gid];
}

extern "C" void kernel_launch(void* const* d_in, const int* in_sizes, int n_in,
                              void* d_out, int out_size, void* d_ws, size_t ws_size,
                              hipStream_t stream)
{
  const float* w1 = (const float*)d_in[0];
  const float* b1 = (const float*)d_in[1];
  const float* w2 = (const float*)d_in[2];
  const float* b2 = (const float*)d_in[3];
  const float* w3 = (const float*)d_in[4];
  const float* b3 = (const float*)d_in[5];
  float* out = (float*)d_out;

  const int NF = 129 * 129 * 129;  // 2146689
  const int NP = 65 * 65 * 65;
  char* ws = (char*)d_ws;
  size_t off = 0;
  auto alloc = [&](size_t bytes) -> void* {
    void* p = (void*)(ws + off);
    off += (bytes + 255) & ~(size_t)255;
    return p;
  };
  float* f_true  = (float*)alloc((size_t)NF * 4);
  float* f_occi  = (float*)alloc((size_t)NF * 4);
  float* f_prevA = (float*)alloc((size_t)NP * 4);
  float* f_prevB = (float*)alloc((size_t)NP * 4);
  float* f_w2t   = (float*)alloc((size_t)HH * HH * 4);
  int*   i_idx   = (int*)alloc((size_t)NF * 4);
  unsigned int* u_cnt  = (unsigned int*)alloc(256);
  unsigned int* u_bcnt = (unsigned int*)alloc(8448 * 4);
  unsigned char* b_b0    = (unsigned char*)alloc(NF);
  unsigned char* b_mism  = (unsigned char*)alloc(NF);
  unsigned char* b_confA = (unsigned char*)alloc(NF);
  unsigned char* b_confB = (unsigned char*)alloc(NF);
  unsigned char* b_calcA = (unsigned char*)alloc(NF);
  unsigned char* b_calcB = (unsigned char*)alloc(NF);
  unsigned char* b_upd   = (unsigned char*)alloc(NF);
  unsigned char* b_cand  = (unsigned char*)alloc(NF);
  unsigned char* b_tmp   = (unsigned char*)alloc(NF);
  (void)ws_size;

  k_prep_w2t<<<16, 256, 0, stream>>>(w2, f_w2t);

  // Level 0: R=17 dense eval; calculated mask all-true.
  {
    int R = 17, s = 8;
    int n = R * R * R;
    int blocks = (n + 255) / 256;
    k_eval_mlp<<<blocks, 256, 0, stream>>>(w1, b1, f_w2t, b2, w3, b3, f_prevA, R, s);
    k_set_ones<<<blocks, 256, 0, stream>>>(b_calcA, n);
  }

  int Rp = 17;
  float* prev = f_prevA;
  unsigned char* calcP = b_calcA;
  unsigned char* calcC = b_calcB;
  for (int li = 1; li <= 3; ++li){
    int R = 2 * Rp - 1;
    int s = 128 / (R - 1);
    unsigned int n = (unsigned int)R * (unsigned int)R * (unsigned int)R;
    int blocks = (int)((n + 255u) / 256u);
    float* occ_out = (li == 3) ? out : ((prev == f_prevA) ? f_prevB : f_prevA);

    if (R == 33){
      k_eval_mlp<<<blocks, 256, 0, stream>>>(w1, b1, f_w2t, b2, w3, b3, f_true, R, s);
      k_resize_boundary<<<blocks, 256, 0, stream>>>(prev, f_true, calcP, f_occi, occ_out, b_b0, b_mism, calcC, R, Rp);
      k_dilate_step<<<blocks, 256, 0, stream>>>(b_b0,    b_mism, calcC, b_confA, b_upd, R, 1, 0, f_true, occ_out);
      k_dilate_step<<<blocks, 256, 0, stream>>>(b_confA, b_mism, calcC, b_confB, b_upd, R, 0, 0, f_true, occ_out);
      k_dilate_step<<<blocks, 256, 0, stream>>>(b_confB, b_mism, calcC, b_confA, b_upd, R, 0, 1, f_true, occ_out);
    } else {
      // sparse path: eval only on C = dilate^3(seed) (separable 7-box)
      k_resize_b0<<<blocks, 256, 0, stream>>>(prev, calcP, f_occi, occ_out, b_b0, calcC,
                                              b_confA, b_confB, b_upd, R, Rp);
      k_dil7x<<<blocks, 256, 0, stream>>>(b_b0,  b_tmp,  R);
      k_dil7y<<<blocks, 256, 0, stream>>>(b_tmp, b_cand, R);
      k_dil7z_count<<<blocks, 256, 0, stream>>>(b_cand, b_tmp, u_bcnt, R);
      k_scan<<<1, 1024, 0, stream>>>(u_bcnt, (unsigned int)blocks, u_cnt);
      k_scatter<<<blocks, 256, 0, stream>>>(b_tmp, u_bcnt, i_idx, n);
      k_eval_sparse<<<blocks, 256, 0, stream>>>(
          w1, b1, f_w2t, b2, w3, b3, i_idx, u_cnt, f_occi, f_true, b_mism, R, s, n);
      int sblocks = blocks < 4096 ? blocks : 4096;
      k_dilate_sparse<<<sblocks, 256, 0, stream>>>(i_idx, u_cnt, b_b0,    b_mism, calcC, b_confA, b_upd, R, 0, f_true, occ_out, n);
      k_dilate_sparse<<<sblocks, 256, 0, stream>>>(i_idx, u_cnt, b_confA, b_mism, calcC, b_confB, b_upd, R, 0, f_true, occ_out, n);
      k_dilate_sparse<<<sblocks, 256, 0, stream>>>(i_idx, u_cnt, b_confB, b_mism, calcC, b_confA, b_upd, R, 1, f_true, occ_out, n);
    }

    prev = occ_out;
    unsigned char* tmpc = calcP; calcP = calcC; calcC = tmpc;
    Rp = R;
  }
  (void)in_sizes; (void)n_in; (void)out_size;
}